// Round 15
// baseline (149.736 us; speedup 1.0000x reference)
//
#include <hip/hip_runtime.h>

#define B 16
#define P 32768
#define NG 128
#define KTOP 4
#define NBX 32
#define NBY 32
#define NBB (NBX * NBY)          // 1024 bins per batch
#define SUB 16                   // sub-blocks per batch for sort
#define SUBP (P / SUB)           // 2048 priors per sort block
typedef unsigned long long u64;
typedef unsigned int u32;

// bucket map for left/bottom edge; monotone non-decreasing in fp (add, mul, trunc>=0)
__device__ __forceinline__ int bkt(float v) {
    int k = (int)((v + 0.08f) * 32.0f);
    return k < 0 ? 0 : (k > 31 ? 31 : k);
}

__device__ __forceinline__ void ceu(u64 &x, u64 &y) {
    u64 a = x, b = y; bool gt = a > b;
    x = gt ? a : b;  y = gt ? b : a;
}
__device__ __forceinline__ void cef(float &x, float &y) {
    float h = fmaxf(x, y), l = fminf(x, y); x = h; y = l;
}

// branchless stable sorted-desc top-4 insert of key x
#define INS4(x, a0, a1, a2, a3)                                   \
    {                                                             \
        bool g0 = (x) > a0, g1 = (x) > a1, g2 = (x) > a2, g3 = (x) > a3; \
        u64 n3 = g2 ? a2 : (g3 ? (x) : a3);                       \
        u64 n2 = g1 ? a1 : (g2 ? (x) : a2);                       \
        u64 n1 = g0 ? a0 : (g1 ? (x) : a1);                       \
        u64 n0 = g0 ? (x) : a0;                                   \
        a0 = n0; a1 = n1; a2 = n2; a3 = n3;                       \
    }

// IoU (bit-exact vs numpy fp32: no contraction, IEEE div, same op order) -> u64 key
#define IOUKEY(q, oi, dst)                                        \
    {                                                             \
        float ap = ((q).z - (q).x) * ((q).w - (q).y);             \
        float ltx = fmaxf(t0, (q).x), lty = fmaxf(t1, (q).y);     \
        float rbx = fminf(t2, (q).z), rby = fminf(t3, (q).w);     \
        float wx = fmaxf(rbx - ltx, 0.0f);                        \
        float wy = fmaxf(rby - lty, 0.0f);                        \
        float inter = wx * wy;                                    \
        float iou = inter / ((areaT + ap) - inter);               \
        dst = ((u64)__float_as_uint(iou) << 32) | (u32)(~(oi));   \
    }

// ---------- kernel A: per-(batch,sub) local histogram + per-sub wh-max + queue reset ----------
__global__ __launch_bounds__(256)
void k_hist(const float* __restrict__ rois, u32* __restrict__ cnt, float* __restrict__ whm,
            u32* __restrict__ qctr)
{
    const int b = blockIdx.x >> 4, sub = blockIdx.x & 15;
    const int tid = threadIdx.x;
    if (blockIdx.x == 0 && tid < 8) qctr[tid] = 0;   // reset k_main's work queues
    __shared__ u32 h[NBB];
    __shared__ float red[8];
    for (int j = tid; j < NBB; j += 256) h[j] = 0;
    __syncthreads();

    const float4* __restrict__ pv = (const float4*)(rois + ((size_t)(2 * b + 1)) * P * 4);
    float wmax = 0.f, hmax = 0.f;
    #pragma unroll
    for (int it = 0; it < SUBP / 256; ++it) {
        float4 q = pv[sub * SUBP + it * 256 + tid];
        atomicAdd(&h[bkt(q.x) * NBY + bkt(q.y)], 1u);
        wmax = fmaxf(wmax, q.z - q.x);
        hmax = fmaxf(hmax, q.w - q.y);
    }
    #pragma unroll
    for (int d = 32; d >= 1; d >>= 1) {
        wmax = fmaxf(wmax, __shfl_down(wmax, d, 64));
        hmax = fmaxf(hmax, __shfl_down(hmax, d, 64));
    }
    if ((tid & 63) == 0) { red[(tid >> 6) * 2] = wmax; red[(tid >> 6) * 2 + 1] = hmax; }
    __syncthreads();
    for (int j = tid; j < NBB; j += 256) cnt[(size_t)blockIdx.x * NBB + j] = h[j];
    if (tid == 0) {
        whm[blockIdx.x * 2 + 0] = fmaxf(fmaxf(red[0], red[2]), fmaxf(red[4], red[6]));
        whm[blockIdx.x * 2 + 1] = fmaxf(fmaxf(red[1], red[3]), fmaxf(red[5], red[7]));
    }
}

// ---------- kernel B: fused scan (recomputed per block) + scatter ----------
__global__ __launch_bounds__(256)
void k_scat(const float* __restrict__ rois, const u32* __restrict__ cnt,
            float4* __restrict__ sbox, u32* __restrict__ sidx, u32* __restrict__ off)
{
    const int b = blockIdx.x >> 4, sub = blockIdx.x & 15;
    const int tid = threadIdx.x;
    const int lane = tid & 63, wv = tid >> 6;
    __shared__ u32 cur[NBB];
    __shared__ u32 wpart[4];

    u32 bintot[4] = {0, 0, 0, 0};
    u32 below[4]  = {0, 0, 0, 0};
    #pragma unroll
    for (int k = 0; k < SUB; ++k) {
        #pragma unroll
        for (int m = 0; m < 4; ++m) {
            u32 v = cnt[(size_t)(b * SUB + k) * NBB + 4 * tid + m];
            bintot[m] += v;
            if (k < sub) below[m] += v;
        }
    }
    u32 s_local = bintot[0] + bintot[1] + bintot[2] + bintot[3];
    u32 incl = s_local;
    #pragma unroll
    for (int d = 1; d < 64; d <<= 1) {
        u32 v = __shfl_up(incl, d, 64);
        if (lane >= d) incl += v;
    }
    if (lane == 63) wpart[wv] = incl;
    __syncthreads();
    u32 wbase = 0;
    #pragma unroll
    for (int w = 0; w < 4; ++w) if (w < wv) wbase += wpart[w];

    u32 run = wbase + incl - s_local;
    #pragma unroll
    for (int m = 0; m < 4; ++m) {
        cur[4 * tid + m] = run + below[m];
        if (sub == 0) off[b * (NBB + 1) + 4 * tid + m] = run;
        run += bintot[m];
    }
    if (sub == 0 && tid == 0) off[b * (NBB + 1) + NBB] = P;
    __syncthreads();

    const float4* __restrict__ pv = (const float4*)(rois + ((size_t)(2 * b + 1)) * P * 4);
    #pragma unroll
    for (int it = 0; it < SUBP / 256; ++it) {
        int i = sub * SUBP + it * 256 + tid;
        float4 q = pv[i];
        u32 slot = atomicAdd(&cur[bkt(q.x) * NBY + bkt(q.y)], 1u);  // order irrelevant: u64 keys
        sbox[(size_t)b * P + slot] = q;
        sidx[(size_t)b * P + slot] = (u32)i;
    }
}

// ---------- kernel C: persistent blocks + per-XCD queue; windowed exact top-4 + encode ----------
// launch_bounds (256,4): 128-VGPR budget so the depth-2 pipeline does NOT spill
// (R13's (256,8) forced a 64-VGPR cap -> 77 MB scratch writes, 2x regression).
__global__ __launch_bounds__(256, 4)
void k_main(const float* __restrict__ rois, const float* __restrict__ targets,
            const float4* __restrict__ sbox, const u32* __restrict__ sidx,
            const u32* __restrict__ off, const float* __restrict__ whm,
            u32* __restrict__ qctr, float* __restrict__ out)
{
    #pragma clang fp contract(off)

    const int xcd = blockIdx.x & 7;       // 512 blocks: 64 per XCD slot, 2 batches each
    const int tid = threadIdx.x;
    const int lane = tid & 63, wv = tid >> 6;

    __shared__ float sf[4][4];
    __shared__ u64   sm[4][4];
    __shared__ int   seg_lo[NBX], seg_hi[NBX];
    __shared__ int   sh_t;

    for (;;) {
        if (tid == 0) sh_t = (int)atomicAdd(&qctr[xcd], 1u);
        __syncthreads();
        const int t = sh_t;
        if (t >= 2 * NG) break;           // 256 truths per XCD pair
        const int b = xcd * 2 + (t & 1);
        const int g = t >> 1;

        const float* tp = targets + ((size_t)(b * NG + g)) * 4;
        const float t0 = tp[0], t1 = tp[1], t2 = tp[2], t3 = tp[3];
        const float areaT = (t2 - t0) * (t3 - t1);
        const float gw = t2 - t0, gh = t3 - t1;

        const float4* __restrict__ boxb = sbox + (size_t)b * P;
        const u32*    __restrict__ idxb = sidx + (size_t)b * P;
        const u32*    __restrict__ offb = off + b * (NBB + 1);

        // ---- stage 0: coalesced subsample (32 lane-contiguous runs of 64) -> lb ----
        float w0 = -1.f, w1 = -1.f, w2 = -1.f, w3 = -1.f;
        #pragma unroll
        for (int it = 0; it < 8; ++it) {
            float4 q = boxb[(it * 4 + wv) * (P / 32) + lane];
            float ap = (q.z - q.x) * (q.w - q.y);
            float ltx = fmaxf(t0, q.x), lty = fmaxf(t1, q.y);
            float rbx = fminf(t2, q.z), rby = fminf(t3, q.w);
            float wx = fmaxf(rbx - ltx, 0.0f);
            float wy = fmaxf(rby - lty, 0.0f);
            float inter = wx * wy;
            float iou = inter / ((areaT + ap) - inter);
            float x = iou, hh;
            hh = fmaxf(w0, x); x = fminf(w0, x); w0 = hh;
            hh = fmaxf(w1, x); x = fminf(w1, x); w1 = hh;
            hh = fmaxf(w2, x); x = fminf(w2, x); w2 = hh;
            w3 = fmaxf(w3, x);
        }
        #pragma unroll
        for (int d = 32; d >= 1; d >>= 1) {
            float n0 = __shfl_down(w0, d, 64);
            float n1 = __shfl_down(w1, d, 64);
            float n2 = __shfl_down(w2, d, 64);
            float n3 = __shfl_down(w3, d, 64);
            cef(w0, n3); cef(w1, n2); cef(w2, n1); cef(w3, n0);
            cef(w0, w2); cef(w1, w3); cef(w0, w1); cef(w2, w3);
        }
        if (lane == 0) { sf[wv][0] = w0; sf[wv][1] = w1; sf[wv][2] = w2; sf[wv][3] = w3; }
        __syncthreads();

        // wave 0 (all lanes redundantly): lb + window bounds; lanes 0..31 fill seg table
        if (wv == 0) {
            float m0 = -1.f, m1 = -1.f, m2 = -1.f, m3 = -1.f;
            #pragma unroll
            for (int j = 0; j < 16; ++j) {
                float x = sf[j >> 2][j & 3], hh;
                hh = fmaxf(m0, x); x = fminf(m0, x); m0 = hh;
                hh = fmaxf(m1, x); x = fminf(m1, x); m1 = hh;
                hh = fmaxf(m2, x); x = fminf(m2, x); m2 = hh;
                m3 = fmaxf(m3, x);
            }
            float wm = 0.f, hm = 0.f;
            #pragma unroll
            for (int k = 0; k < SUB; ++k) {
                wm = fmaxf(wm, whm[(b * SUB + k) * 2 + 0]);
                hm = fmaxf(hm, whm[(b * SUB + k) * 2 + 1]);
            }
            float lb = m3 * 0.999f;   // relative margin 1e-3 >> fp rounding of bound exprs
            int bxlo = 0, bxhi = 31, bylo = 0, byhi = 31;
            if (lb > 1e-6f) {
                // necessary for iou>=lb: p0 in [t0+lb*gw-wm, t2-lb*gw], y analog.
                // bkt monotone => exact bucket bounds; 1e-5 abs slack >> 5e-7 fp error.
                bxlo = bkt(t0 + lb * gw - wm - 1e-5f);
                bxhi = bkt(t2 - lb * gw + 1e-5f);
                bylo = bkt(t1 + lb * gh - hm - 1e-5f);
                byhi = bkt(t3 - lb * gh + 1e-5f);
            }
            if (lane < NBX) {
                bool inx = (lane >= bxlo) && (lane <= bxhi);
                int lo = (int)offb[lane * NBY + bylo];
                int hi = (int)offb[lane * NBY + byhi + 1];
                seg_lo[lane] = lo;
                seg_hi[lane] = inx ? hi : lo;   // empty column outside window
            }
        }
        __syncthreads();

        // ---- stage 1: wave-per-column, 2-wide chains + DEPTH-2 pipeline ----
        u64 a0 = 0, a1 = 0, a2 = 0, a3 = 0;      // chain A (even 64-groups)
        u64 c0 = 0, c1 = 0, c2 = 0, c3 = 0;      // chain B (odd 64-groups)
        for (int s = wv; s < NBX; s += 4) {
            const int lo = seg_lo[s];
            const int n = seg_hi[s] - lo;        // wave-uniform trip count
            const float4* __restrict__ bp = boxb + lo;
            const u32*    __restrict__ ip = idxb + lo;

            float4 qa0 = {0,0,0,0}, qb0 = {0,0,0,0}, qa1 = {0,0,0,0}, qb1 = {0,0,0,0};
            u32 oa0 = 0, ob0 = 0, oa1 = 0, ob1 = 0;
            if (lane < n)       { qa0 = bp[lane];       oa0 = ip[lane]; }
            if (lane + 64 < n)  { qb0 = bp[lane + 64];  ob0 = ip[lane + 64]; }
            if (lane + 128 < n) { qa1 = bp[lane + 128]; oa1 = ip[lane + 128]; }
            if (lane + 192 < n) { qb1 = bp[lane + 192]; ob1 = ip[lane + 192]; }

            for (int base = 0; base < n; base += 128) {
                float4 qa2 = qa1, qb2 = qb1; u32 oa2 = oa1, ob2 = ob1;
                const int ja = base + 256 + lane, jb = base + 320 + lane;
                if (ja < n) { qa2 = bp[ja]; oa2 = ip[ja]; }
                if (jb < n) { qb2 = bp[jb]; ob2 = ip[jb]; }

                if (base + lane < n) {
                    u64 x; IOUKEY(qa0, oa0, x);
                    INS4(x, a0, a1, a2, a3);
                }
                if (base + 64 + lane < n) {
                    u64 x; IOUKEY(qb0, ob0, x);
                    INS4(x, c0, c1, c2, c3);
                }
                qa0 = qa1; oa0 = oa1; qb0 = qb1; ob0 = ob1;
                qa1 = qa2; oa1 = oa2; qb1 = qb2; ob1 = ob2;
            }
        }
        // merge chain B into A (both sorted desc): bitonic 8->4
        ceu(a0, c3); ceu(a1, c2); ceu(a2, c1); ceu(a3, c0);
        ceu(a0, a2); ceu(a1, a3); ceu(a0, a1); ceu(a2, a3);

        #pragma unroll
        for (int d = 32; d >= 1; d >>= 1) {
            u64 n0 = __shfl_down(a0, d, 64);
            u64 n1 = __shfl_down(a1, d, 64);
            u64 n2 = __shfl_down(a2, d, 64);
            u64 n3 = __shfl_down(a3, d, 64);
            ceu(a0, n3); ceu(a1, n2); ceu(a2, n1); ceu(a3, n0);
            ceu(a0, a2); ceu(a1, a3); ceu(a0, a1); ceu(a2, a3);
        }
        if (lane == 0) { sm[wv][0] = a0; sm[wv][1] = a1; sm[wv][2] = a2; sm[wv][3] = a3; }
        __syncthreads();

        if (tid == 0) {
            u64 f0 = 0, f1 = 0, f2 = 0, f3 = 0;
            #pragma unroll
            for (int j = 0; j < 16; ++j) {
                u64 x = sm[j >> 2][j & 3];
                INS4(x, f0, f1, f2, f3);
            }
            const float gcx = (t0 + t2) * 0.5f;
            const float gcy = (t1 + t3) * 0.5f;
            const float4* __restrict__ pv =
                (const float4*)(rois + ((size_t)(2 * b + 1)) * P * 4);
            float4* __restrict__ o4 = (float4*)out;

            u64 ks[KTOP] = {f0, f1, f2, f3};
            #pragma unroll
            for (int k = 0; k < KTOP; ++k) {
                int idx = (int)(~(u32)ks[k]) & (P - 1);   // decode original prior index
                float4 q = pv[idx];
                float pcx = (q.x + q.z) * 0.5f;
                float pcy = (q.y + q.w) * 0.5f;
                float pw  = q.z - q.x;
                float ph  = q.w - q.y;
                float4 r;
                r.x = (gcx - pcx) / (0.1f * pw);
                r.y = (gcy - pcy) / (0.1f * ph);
                r.z = logf(gw / pw) / 0.2f;
                r.w = logf(gh / ph) / 0.2f;
                o4[((size_t)(b * NG + g)) * KTOP + k] = r;
            }
        }
        __syncthreads();   // protect LDS tables before next queue item
    }
}

extern "C" void kernel_launch(void* const* d_in, const int* in_sizes, int n_in,
                              void* d_out, int out_size, void* d_ws, size_t ws_size,
                              hipStream_t stream) {
    const float* rois    = (const float*)d_in[0];
    const float* targets = (const float*)d_in[1];
    float* out = (float*)d_out;

    char* w = (char*)d_ws;
    float4* sbox = (float4*)(w);                                    // 8 MB
    u32*    sidx = (u32*)  (w + (size_t)B * P * 16);                // 2 MB
    u32*    cnt  = (u32*)  (w + (size_t)B * P * 20);                // 1 MB
    u32*    off  = (u32*)  (w + (size_t)B * P * 24);                // 65.6 KB
    float*  whm  = (float*)(w + (size_t)B * P * 24 + 66560);        // 2 KB
    u32*    qctr = (u32*)  (w + (size_t)B * P * 24 + 66560 + 2048); // 32 B

    k_hist<<<dim3(B * SUB), dim3(256), 0, stream>>>(rois, cnt, whm, qctr);
    k_scat<<<dim3(B * SUB), dim3(256), 0, stream>>>(rois, cnt, sbox, sidx, off);
    k_main<<<dim3(512),     dim3(256), 0, stream>>>(rois, targets, sbox, sidx, off, whm, qctr, out);
}

// Round 18
// 132.671 us; speedup vs baseline: 1.1286x; 1.1286x over previous
//
#include <hip/hip_runtime.h>

#define B 16
#define P 32768
#define NG 128
#define KTOP 4
#define NBX 32
#define NBY 32
#define NBB (NBX * NBY)          // 1024 bins per batch
#define SUB 16                   // sub-blocks per batch for sort
#define SUBP (P / SUB)           // 2048 priors per sort block
typedef unsigned long long u64;
typedef unsigned int u32;

// bucket map for left/bottom edge; monotone non-decreasing in fp (add, mul, trunc>=0)
__device__ __forceinline__ int bkt(float v) {
    int k = (int)((v + 0.08f) * 32.0f);
    return k < 0 ? 0 : (k > 31 ? 31 : k);
}

__device__ __forceinline__ void ceu(u64 &x, u64 &y) {
    u64 a = x, b = y; bool gt = a > b;
    x = gt ? a : b;  y = gt ? b : a;
}
__device__ __forceinline__ void cef(float &x, float &y) {
    float h = fmaxf(x, y), l = fminf(x, y); x = h; y = l;
}

// branchless stable sorted-desc top-4 insert of key x
#define INS4(x, a0, a1, a2, a3)                                   \
    {                                                             \
        bool g0 = (x) > a0, g1 = (x) > a1, g2 = (x) > a2, g3 = (x) > a3; \
        u64 n3 = g2 ? a2 : (g3 ? (x) : a3);                       \
        u64 n2 = g1 ? a1 : (g2 ? (x) : a2);                       \
        u64 n1 = g0 ? a0 : (g1 ? (x) : a1);                       \
        u64 n0 = g0 ? (x) : a0;                                   \
        a0 = n0; a1 = n1; a2 = n2; a3 = n3;                       \
    }

// IoU (bit-exact vs numpy fp32: no contraction, IEEE div, same op order) -> u64 key
#define IOUKEY(q, oi, dst)                                        \
    {                                                             \
        float ap = ((q).z - (q).x) * ((q).w - (q).y);             \
        float ltx = fmaxf(t0, (q).x), lty = fmaxf(t1, (q).y);     \
        float rbx = fminf(t2, (q).z), rby = fminf(t3, (q).w);     \
        float wx = fmaxf(rbx - ltx, 0.0f);                        \
        float wy = fmaxf(rby - lty, 0.0f);                        \
        float inter = wx * wy;                                    \
        float iou = inter / ((areaT + ap) - inter);               \
        dst = ((u64)__float_as_uint(iou) << 32) | (u32)(~(oi));   \
    }

// ---------- kernel A: per-(batch,sub) histogram + per-sub wh-max ----------
__global__ __launch_bounds__(256)
void k_hist(const float* __restrict__ rois, u32* __restrict__ cnt, float* __restrict__ whm)
{
    const int b = blockIdx.x >> 4, sub = blockIdx.x & 15;
    const int tid = threadIdx.x;
    __shared__ u32 h[NBB];
    __shared__ float red[8];
    for (int j = tid; j < NBB; j += 256) h[j] = 0;
    __syncthreads();

    const float4* __restrict__ pv = (const float4*)(rois + ((size_t)(2 * b + 1)) * P * 4);
    float wmax = 0.f, hmax = 0.f;
    #pragma unroll
    for (int it = 0; it < SUBP / 256; ++it) {
        float4 q = pv[sub * SUBP + it * 256 + tid];
        atomicAdd(&h[bkt(q.x) * NBY + bkt(q.y)], 1u);
        wmax = fmaxf(wmax, q.z - q.x);
        hmax = fmaxf(hmax, q.w - q.y);
    }
    #pragma unroll
    for (int d = 32; d >= 1; d >>= 1) {
        wmax = fmaxf(wmax, __shfl_down(wmax, d, 64));
        hmax = fmaxf(hmax, __shfl_down(hmax, d, 64));
    }
    if ((tid & 63) == 0) { red[(tid >> 6) * 2] = wmax; red[(tid >> 6) * 2 + 1] = hmax; }
    __syncthreads();
    for (int j = tid; j < NBB; j += 256) cnt[(size_t)blockIdx.x * NBB + j] = h[j];
    if (tid == 0) {
        whm[blockIdx.x * 2 + 0] = fmaxf(fmaxf(red[0], red[2]), fmaxf(red[4], red[6]));
        whm[blockIdx.x * 2 + 1] = fmaxf(fmaxf(red[1], red[3]), fmaxf(red[5], red[7]));
    }
}

// ---------- kernel B: fused scan (recomputed per block) + scatter ----------
__global__ __launch_bounds__(256)
void k_scat(const float* __restrict__ rois, const u32* __restrict__ cnt,
            float4* __restrict__ sbox, u32* __restrict__ sidx, u32* __restrict__ off)
{
    const int b = blockIdx.x >> 4, sub = blockIdx.x & 15;
    const int tid = threadIdx.x;
    const int lane = tid & 63, wv = tid >> 6;
    __shared__ u32 cur[NBB];
    __shared__ u32 wpart[4];

    u32 bintot[4] = {0, 0, 0, 0};
    u32 below[4]  = {0, 0, 0, 0};
    #pragma unroll
    for (int k = 0; k < SUB; ++k) {
        #pragma unroll
        for (int m = 0; m < 4; ++m) {
            u32 v = cnt[(size_t)(b * SUB + k) * NBB + 4 * tid + m];
            bintot[m] += v;
            if (k < sub) below[m] += v;
        }
    }
    u32 s_local = bintot[0] + bintot[1] + bintot[2] + bintot[3];
    u32 incl = s_local;
    #pragma unroll
    for (int d = 1; d < 64; d <<= 1) {
        u32 v = __shfl_up(incl, d, 64);
        if (lane >= d) incl += v;
    }
    if (lane == 63) wpart[wv] = incl;
    __syncthreads();
    u32 wbase = 0;
    #pragma unroll
    for (int w = 0; w < 4; ++w) if (w < wv) wbase += wpart[w];

    u32 run = wbase + incl - s_local;
    #pragma unroll
    for (int m = 0; m < 4; ++m) {
        cur[4 * tid + m] = run + below[m];
        if (sub == 0) off[b * (NBB + 1) + 4 * tid + m] = run;
        run += bintot[m];
    }
    if (sub == 0 && tid == 0) off[b * (NBB + 1) + NBB] = P;
    __syncthreads();

    const float4* __restrict__ pv = (const float4*)(rois + ((size_t)(2 * b + 1)) * P * 4);
    #pragma unroll
    for (int it = 0; it < SUBP / 256; ++it) {
        int i = sub * SUBP + it * 256 + tid;
        float4 q = pv[i];
        u32 slot = atomicAdd(&cur[bkt(q.x) * NBY + bkt(q.y)], 1u);  // order irrelevant: u64 keys
        sbox[(size_t)b * P + slot] = q;
        sidx[(size_t)b * P + slot] = (u32)i;
    }
}

// ---------- kernel C: half-truth blocks -> top-4 keys per half ----------
// GRID = 2*B*NG = 4096 (R16/R17 launched 8192: phantom blocks read OOB targets and
// clobbered other batches' cand slots -> absmax 146/365. Fixed + guarded.)
// launch_bounds (256,4): 128-VGPR budget so the depth-2 pipeline does NOT spill (R13 lesson).
__global__ __launch_bounds__(256, 4)
void k_main(const float* __restrict__ targets,
            const float4* __restrict__ sbox, const u32* __restrict__ sidx,
            const u32* __restrict__ off, const float* __restrict__ whm,
            u64* __restrict__ cand)
{
    #pragma clang fp contract(off)

    const int blk = blockIdx.x;                           // 4096
    const int b    = ((blk & 7) << 1) | ((blk >> 3) & 1); // 2 batches per XCD; halves same XCD
    const int r    = blk >> 4;                            // 0..255
    if (r >= 2 * NG) return;                              // defensive
    const int half = r & 1;
    const int g    = r >> 1;                              // 0..127
    const int tid = threadIdx.x;
    const int lane = tid & 63, wv = tid >> 6;

    const float* tp = targets + ((size_t)(b * NG + g)) * 4;
    const float t0 = tp[0], t1 = tp[1], t2 = tp[2], t3 = tp[3];
    const float areaT = (t2 - t0) * (t3 - t1);
    const float gw = t2 - t0, gh = t3 - t1;

    const float4* __restrict__ boxb = sbox + (size_t)b * P;
    const u32*    __restrict__ idxb = sidx + (size_t)b * P;
    const u32*    __restrict__ offb = off + b * (NBB + 1);

    __shared__ float sf[4][4];
    __shared__ u64   sm[4][4];
    __shared__ int   seg_lo[NBX], seg_hi[NBX];

    // ---- stage 0: coalesced subsample (16 lane-contiguous runs of 64 = 1024) -> lb ----
    float w0 = -1.f, w1 = -1.f, w2 = -1.f, w3 = -1.f;
    #pragma unroll
    for (int it = 0; it < 4; ++it) {
        float4 q = boxb[(it * 4 + wv) * (P / 16) + lane];
        float ap = (q.z - q.x) * (q.w - q.y);
        float ltx = fmaxf(t0, q.x), lty = fmaxf(t1, q.y);
        float rbx = fminf(t2, q.z), rby = fminf(t3, q.w);
        float wx = fmaxf(rbx - ltx, 0.0f);
        float wy = fmaxf(rby - lty, 0.0f);
        float inter = wx * wy;
        float iou = inter / ((areaT + ap) - inter);
        float x = iou, hh;
        hh = fmaxf(w0, x); x = fminf(w0, x); w0 = hh;
        hh = fmaxf(w1, x); x = fminf(w1, x); w1 = hh;
        hh = fmaxf(w2, x); x = fminf(w2, x); w2 = hh;
        w3 = fmaxf(w3, x);
    }
    #pragma unroll
    for (int d = 32; d >= 1; d >>= 1) {
        float n0 = __shfl_down(w0, d, 64);
        float n1 = __shfl_down(w1, d, 64);
        float n2 = __shfl_down(w2, d, 64);
        float n3 = __shfl_down(w3, d, 64);
        cef(w0, n3); cef(w1, n2); cef(w2, n1); cef(w3, n0);
        cef(w0, w2); cef(w1, w3); cef(w0, w1); cef(w2, w3);
    }
    if (lane == 0) { sf[wv][0] = w0; sf[wv][1] = w1; sf[wv][2] = w2; sf[wv][3] = w3; }
    __syncthreads();

    // wave 0 (all lanes redundantly): lb + window bounds; lanes 0..31 fill seg table
    if (wv == 0) {
        float m0 = -1.f, m1 = -1.f, m2 = -1.f, m3 = -1.f;
        #pragma unroll
        for (int j = 0; j < 16; ++j) {
            float x = sf[j >> 2][j & 3], hh;
            hh = fmaxf(m0, x); x = fminf(m0, x); m0 = hh;
            hh = fmaxf(m1, x); x = fminf(m1, x); m1 = hh;
            hh = fmaxf(m2, x); x = fminf(m2, x); m2 = hh;
            m3 = fmaxf(m3, x);
        }
        float wm = 0.f, hm = 0.f;
        #pragma unroll
        for (int k = 0; k < SUB; ++k) {
            wm = fmaxf(wm, whm[(b * SUB + k) * 2 + 0]);
            hm = fmaxf(hm, whm[(b * SUB + k) * 2 + 1]);
        }
        float lb = m3 * 0.999f;   // subset 4th-best <= true v3; margin >> fp rounding
        int bxlo = 0, bxhi = 31, bylo = 0, byhi = 31;
        if (lb > 1e-6f) {
            // necessary for iou>=lb: p0 in [t0+lb*gw-wm, t2-lb*gw], y analog.
            // bkt monotone => exact bucket bounds; 1e-5 abs slack >> 5e-7 fp error.
            bxlo = bkt(t0 + lb * gw - wm - 1e-5f);
            bxhi = bkt(t2 - lb * gw + 1e-5f);
            bylo = bkt(t1 + lb * gh - hm - 1e-5f);
            byhi = bkt(t3 - lb * gh + 1e-5f);
        }
        if (lane < NBX) {
            bool inx = (lane >= bxlo) && (lane <= bxhi);
            int lo = (int)offb[lane * NBY + bylo];
            int hi = (int)offb[lane * NBY + byhi + 1];
            seg_lo[lane] = lo;
            seg_hi[lane] = inx ? hi : lo;   // empty column outside window
        }
    }
    __syncthreads();

    // ---- stage 1: this half scans columns with (s&1)==half; wave wv takes s=half+2*wv+8k ----
    u64 a0 = 0, a1 = 0, a2 = 0, a3 = 0;      // chain A (even 64-groups)
    u64 c0 = 0, c1 = 0, c2 = 0, c3 = 0;      // chain B (odd 64-groups)
    for (int k = 0; k < 4; ++k) {
        const int s = half + 2 * wv + 8 * k;
        const int lo = seg_lo[s];
        const int n = seg_hi[s] - lo;        // wave-uniform trip count
        const float4* __restrict__ bp = boxb + lo;
        const u32*    __restrict__ ip = idxb + lo;

        float4 qa0 = {0,0,0,0}, qb0 = {0,0,0,0}, qa1 = {0,0,0,0}, qb1 = {0,0,0,0};
        u32 oa0 = 0, ob0 = 0, oa1 = 0, ob1 = 0;
        if (lane < n)       { qa0 = bp[lane];       oa0 = ip[lane]; }
        if (lane + 64 < n)  { qb0 = bp[lane + 64];  ob0 = ip[lane + 64]; }
        if (lane + 128 < n) { qa1 = bp[lane + 128]; oa1 = ip[lane + 128]; }
        if (lane + 192 < n) { qb1 = bp[lane + 192]; ob1 = ip[lane + 192]; }

        for (int base = 0; base < n; base += 128) {
            float4 qa2 = qa1, qb2 = qb1; u32 oa2 = oa1, ob2 = ob1;
            const int ja = base + 256 + lane, jb = base + 320 + lane;
            if (ja < n) { qa2 = bp[ja]; oa2 = ip[ja]; }
            if (jb < n) { qb2 = bp[jb]; ob2 = ip[jb]; }

            if (base + lane < n) {
                u64 x; IOUKEY(qa0, oa0, x);
                INS4(x, a0, a1, a2, a3);
            }
            if (base + 64 + lane < n) {
                u64 x; IOUKEY(qb0, ob0, x);
                INS4(x, c0, c1, c2, c3);
            }
            qa0 = qa1; oa0 = oa1; qb0 = qb1; ob0 = ob1;
            qa1 = qa2; oa1 = oa2; qb1 = qb2; ob1 = ob2;
        }
    }
    // merge chain B into A (both sorted desc): bitonic 8->4
    ceu(a0, c3); ceu(a1, c2); ceu(a2, c1); ceu(a3, c0);
    ceu(a0, a2); ceu(a1, a3); ceu(a0, a1); ceu(a2, a3);

    #pragma unroll
    for (int d = 32; d >= 1; d >>= 1) {
        u64 n0 = __shfl_down(a0, d, 64);
        u64 n1 = __shfl_down(a1, d, 64);
        u64 n2 = __shfl_down(a2, d, 64);
        u64 n3 = __shfl_down(a3, d, 64);
        ceu(a0, n3); ceu(a1, n2); ceu(a2, n1); ceu(a3, n0);
        ceu(a0, a2); ceu(a1, a3); ceu(a0, a1); ceu(a2, a3);
    }
    if (lane == 0) { sm[wv][0] = a0; sm[wv][1] = a1; sm[wv][2] = a2; sm[wv][3] = a3; }
    __syncthreads();

    if (tid == 0) {
        u64 f0 = 0, f1 = 0, f2 = 0, f3 = 0;
        #pragma unroll
        for (int j = 0; j < 16; ++j) {
            u64 x = sm[j >> 2][j & 3];
            INS4(x, f0, f1, f2, f3);
        }
        const int tg = b * NG + g;
        u64* my = cand + (size_t)tg * 8 + half * 4;   // consumed by k_enc (stream order)
        my[0] = f0; my[1] = f1; my[2] = f2; my[3] = f3;
    }
}

// ---------- kernel D: merge 8 keys per truth + encode (one thread per truth) ----------
__global__ __launch_bounds__(256)
void k_enc(const float* __restrict__ rois, const float* __restrict__ targets,
           const u64* __restrict__ cand, float* __restrict__ out, int ntruth)
{
    #pragma clang fp contract(off)

    const int tg = blockIdx.x * 256 + threadIdx.x;
    if (tg >= ntruth) return;
    const int b = tg >> 7;                            // NG = 128

    const u64* c = cand + (size_t)tg * 8;
    u64 f0 = 0, f1 = 0, f2 = 0, f3 = 0;
    #pragma unroll
    for (int j = 0; j < 8; ++j) {
        u64 x = c[j];
        INS4(x, f0, f1, f2, f3);
    }

    const float* tp = targets + (size_t)tg * 4;
    const float t0 = tp[0], t1 = tp[1], t2 = tp[2], t3 = tp[3];
    const float gcx = (t0 + t2) * 0.5f;
    const float gcy = (t1 + t3) * 0.5f;
    const float gw  = t2 - t0;
    const float gh  = t3 - t1;

    const float4* __restrict__ pv =
        (const float4*)(rois + ((size_t)(2 * b + 1)) * P * 4);
    float4* __restrict__ o4 = (float4*)out;

    u64 ks[KTOP] = {f0, f1, f2, f3};
    #pragma unroll
    for (int k = 0; k < KTOP; ++k) {
        int idx = (int)(~(u32)ks[k]) & (P - 1);       // decode original prior index
        float4 q = pv[idx];
        float pcx = (q.x + q.z) * 0.5f;
        float pcy = (q.y + q.w) * 0.5f;
        float pw  = q.z - q.x;
        float ph  = q.w - q.y;
        float4 r;
        r.x = (gcx - pcx) / (0.1f * pw);
        r.y = (gcy - pcy) / (0.1f * ph);
        r.z = logf(gw / pw) / 0.2f;
        r.w = logf(gh / ph) / 0.2f;
        o4[(size_t)tg * KTOP + k] = r;
    }
}

extern "C" void kernel_launch(void* const* d_in, const int* in_sizes, int n_in,
                              void* d_out, int out_size, void* d_ws, size_t ws_size,
                              hipStream_t stream) {
    const float* rois    = (const float*)d_in[0];
    const float* targets = (const float*)d_in[1];
    float* out = (float*)d_out;

    char* w = (char*)d_ws;
    float4* sbox = (float4*)(w);                                    // 8 MB
    u32*    sidx = (u32*)  (w + (size_t)B * P * 16);                // 2 MB
    u32*    cnt  = (u32*)  (w + (size_t)B * P * 20);                // 1 MB
    u32*    off  = (u32*)  (w + (size_t)B * P * 24);                // 65.6 KB
    float*  whm  = (float*)(w + (size_t)B * P * 24 + 66560);        // 2 KB
    u64*    cand = (u64*)  (w + (size_t)B * P * 24 + 66560 + 2048); // 128 KB

    const int ntruth = B * NG;                                      // 2048

    k_hist<<<dim3(B * SUB), dim3(256), 0, stream>>>(rois, cnt, whm);
    k_scat<<<dim3(B * SUB), dim3(256), 0, stream>>>(rois, cnt, sbox, sidx, off);
    k_main<<<dim3(2 * B * NG), dim3(256), 0, stream>>>(targets, sbox, sidx, off, whm, cand);
    k_enc <<<dim3((ntruth + 255) / 256), dim3(256), 0, stream>>>(rois, targets, cand, out, ntruth);
}

// Round 19
// 121.298 us; speedup vs baseline: 1.2344x; 1.0938x over previous
//
#include <hip/hip_runtime.h>

#define B 16
#define P 32768
#define NG 128
#define KTOP 4
#define NBX 32
#define NBY 32
#define NBB (NBX * NBY)          // 1024 bins per batch
#define SUB 16                   // sub-blocks per batch for sort
#define SUBP (P / SUB)           // 2048 priors per sort block
typedef unsigned long long u64;
typedef unsigned int u32;

// bucket map for left/bottom edge; monotone non-decreasing in fp (add, mul, trunc>=0)
__device__ __forceinline__ int bkt(float v) {
    int k = (int)((v + 0.08f) * 32.0f);
    return k < 0 ? 0 : (k > 31 ? 31 : k);
}

__device__ __forceinline__ void ceu(u64 &x, u64 &y) {
    u64 a = x, b = y; bool gt = a > b;
    x = gt ? a : b;  y = gt ? b : a;
}
__device__ __forceinline__ void cef(float &x, float &y) {
    float h = fmaxf(x, y), l = fminf(x, y); x = h; y = l;
}

// branchless stable sorted-desc top-4 insert of key x
#define INS4(x, a0, a1, a2, a3)                                   \
    {                                                             \
        bool g0 = (x) > a0, g1 = (x) > a1, g2 = (x) > a2, g3 = (x) > a3; \
        u64 n3 = g2 ? a2 : (g3 ? (x) : a3);                       \
        u64 n2 = g1 ? a1 : (g2 ? (x) : a2);                       \
        u64 n1 = g0 ? a0 : (g1 ? (x) : a1);                       \
        u64 n0 = g0 ? (x) : a0;                                   \
        a0 = n0; a1 = n1; a2 = n2; a3 = n3;                       \
    }

// IoU (bit-exact vs numpy fp32: no contraction, IEEE div, same op order) -> u64 key
#define IOUKEY(q, oi, dst)                                        \
    {                                                             \
        float ap = ((q).z - (q).x) * ((q).w - (q).y);             \
        float ltx = fmaxf(t0, (q).x), lty = fmaxf(t1, (q).y);     \
        float rbx = fminf(t2, (q).z), rby = fminf(t3, (q).w);     \
        float wx = fmaxf(rbx - ltx, 0.0f);                        \
        float wy = fmaxf(rby - lty, 0.0f);                        \
        float inter = wx * wy;                                    \
        float iou = inter / ((areaT + ap) - inter);               \
        dst = ((u64)__float_as_uint(iou) << 32) | (u32)(~(oi));   \
    }

// ---------- kernel A: per-(batch,sub) local histogram + per-sub wh-max ----------
__global__ __launch_bounds__(256)
void k_hist(const float* __restrict__ rois, u32* __restrict__ cnt, float* __restrict__ whm)
{
    const int b = blockIdx.x >> 4, sub = blockIdx.x & 15;
    const int tid = threadIdx.x;
    __shared__ u32 h[NBB];
    __shared__ float red[8];
    for (int j = tid; j < NBB; j += 256) h[j] = 0;
    __syncthreads();

    const float4* __restrict__ pv = (const float4*)(rois + ((size_t)(2 * b + 1)) * P * 4);
    float wmax = 0.f, hmax = 0.f;
    #pragma unroll
    for (int it = 0; it < SUBP / 256; ++it) {
        float4 q = pv[sub * SUBP + it * 256 + tid];
        atomicAdd(&h[bkt(q.x) * NBY + bkt(q.y)], 1u);
        wmax = fmaxf(wmax, q.z - q.x);
        hmax = fmaxf(hmax, q.w - q.y);
    }
    #pragma unroll
    for (int d = 32; d >= 1; d >>= 1) {
        wmax = fmaxf(wmax, __shfl_down(wmax, d, 64));
        hmax = fmaxf(hmax, __shfl_down(hmax, d, 64));
    }
    if ((tid & 63) == 0) { red[(tid >> 6) * 2] = wmax; red[(tid >> 6) * 2 + 1] = hmax; }
    __syncthreads();
    for (int j = tid; j < NBB; j += 256) cnt[(size_t)blockIdx.x * NBB + j] = h[j];
    if (tid == 0) {
        whm[blockIdx.x * 2 + 0] = fmaxf(fmaxf(red[0], red[2]), fmaxf(red[4], red[6]));
        whm[blockIdx.x * 2 + 1] = fmaxf(fmaxf(red[1], red[3]), fmaxf(red[5], red[7]));
    }
}

// ---------- kernel B: fused scan (recomputed per block) + scatter ----------
__global__ __launch_bounds__(256)
void k_scat(const float* __restrict__ rois, const u32* __restrict__ cnt,
            float4* __restrict__ sbox, u32* __restrict__ sidx, u32* __restrict__ off)
{
    const int b = blockIdx.x >> 4, sub = blockIdx.x & 15;
    const int tid = threadIdx.x;
    const int lane = tid & 63, wv = tid >> 6;
    __shared__ u32 cur[NBB];
    __shared__ u32 wpart[4];

    u32 bintot[4] = {0, 0, 0, 0};
    u32 below[4]  = {0, 0, 0, 0};
    #pragma unroll
    for (int k = 0; k < SUB; ++k) {
        #pragma unroll
        for (int m = 0; m < 4; ++m) {
            u32 v = cnt[(size_t)(b * SUB + k) * NBB + 4 * tid + m];
            bintot[m] += v;
            if (k < sub) below[m] += v;
        }
    }
    u32 s_local = bintot[0] + bintot[1] + bintot[2] + bintot[3];
    u32 incl = s_local;
    #pragma unroll
    for (int d = 1; d < 64; d <<= 1) {
        u32 v = __shfl_up(incl, d, 64);
        if (lane >= d) incl += v;
    }
    if (lane == 63) wpart[wv] = incl;
    __syncthreads();
    u32 wbase = 0;
    #pragma unroll
    for (int w = 0; w < 4; ++w) if (w < wv) wbase += wpart[w];

    u32 run = wbase + incl - s_local;
    #pragma unroll
    for (int m = 0; m < 4; ++m) {
        cur[4 * tid + m] = run + below[m];
        if (sub == 0) off[b * (NBB + 1) + 4 * tid + m] = run;
        run += bintot[m];
    }
    if (sub == 0 && tid == 0) off[b * (NBB + 1) + NBB] = P;
    __syncthreads();

    const float4* __restrict__ pv = (const float4*)(rois + ((size_t)(2 * b + 1)) * P * 4);
    #pragma unroll
    for (int it = 0; it < SUBP / 256; ++it) {
        int i = sub * SUBP + it * 256 + tid;
        float4 q = pv[i];
        u32 slot = atomicAdd(&cur[bkt(q.x) * NBY + bkt(q.y)], 1u);  // order irrelevant: u64 keys
        sbox[(size_t)b * P + slot] = q;
        sidx[(size_t)b * P + slot] = (u32)i;
    }
}

// ---------- kernel C: LB subsample + column-segment windowed exact top-4 + encode ----------
// launch_bounds (256,4): 128-VGPR budget so the depth-2 pipeline does NOT spill
// (R13's (256,8) forced a 64-VGPR cap -> 77 MB scratch writes, 2x regression).
__global__ __launch_bounds__(256, 4)
void k_main(const float* __restrict__ rois, const float* __restrict__ targets,
            const float4* __restrict__ sbox, const u32* __restrict__ sidx,
            const u32* __restrict__ off, const float* __restrict__ whm,
            float* __restrict__ out)
{
    #pragma clang fp contract(off)

    const int blk = blockIdx.x;                           // 2048
    const int b   = ((blk & 7) << 1) | ((blk >> 3) & 1);  // 2 batches per XCD
    const int g   = blk >> 4;
    const int tid = threadIdx.x;
    const int lane = tid & 63, wv = tid >> 6;

    const float* tp = targets + ((size_t)(b * NG + g)) * 4;
    const float t0 = tp[0], t1 = tp[1], t2 = tp[2], t3 = tp[3];
    const float areaT = (t2 - t0) * (t3 - t1);
    const float gw = t2 - t0, gh = t3 - t1;

    const float4* __restrict__ boxb = sbox + (size_t)b * P;
    const u32*    __restrict__ idxb = sidx + (size_t)b * P;
    const u32*    __restrict__ offb = off + b * (NBB + 1);

    __shared__ float sf[4][4];
    __shared__ u64   sm[4][4];
    __shared__ int   seg_lo[NBX], seg_hi[NBX];

    // ---- stage 0: coalesced subsample (32 lane-contiguous runs of 64) -> lb ----
    float w0 = -1.f, w1 = -1.f, w2 = -1.f, w3 = -1.f;
    #pragma unroll
    for (int it = 0; it < 8; ++it) {
        float4 q = boxb[(it * 4 + wv) * (P / 32) + lane];
        float ap = (q.z - q.x) * (q.w - q.y);
        float ltx = fmaxf(t0, q.x), lty = fmaxf(t1, q.y);
        float rbx = fminf(t2, q.z), rby = fminf(t3, q.w);
        float wx = fmaxf(rbx - ltx, 0.0f);
        float wy = fmaxf(rby - lty, 0.0f);
        float inter = wx * wy;
        float iou = inter / ((areaT + ap) - inter);
        float x = iou, hh;
        hh = fmaxf(w0, x); x = fminf(w0, x); w0 = hh;
        hh = fmaxf(w1, x); x = fminf(w1, x); w1 = hh;
        hh = fmaxf(w2, x); x = fminf(w2, x); w2 = hh;
        w3 = fmaxf(w3, x);
    }
    #pragma unroll
    for (int d = 32; d >= 1; d >>= 1) {
        float n0 = __shfl_down(w0, d, 64);
        float n1 = __shfl_down(w1, d, 64);
        float n2 = __shfl_down(w2, d, 64);
        float n3 = __shfl_down(w3, d, 64);
        cef(w0, n3); cef(w1, n2); cef(w2, n1); cef(w3, n0);
        cef(w0, w2); cef(w1, w3); cef(w0, w1); cef(w2, w3);
    }
    if (lane == 0) { sf[wv][0] = w0; sf[wv][1] = w1; sf[wv][2] = w2; sf[wv][3] = w3; }
    __syncthreads();

    // wave 0 (all lanes redundantly): lb + window bounds; lanes 0..31 fill seg table
    if (wv == 0) {
        float m0 = -1.f, m1 = -1.f, m2 = -1.f, m3 = -1.f;
        #pragma unroll
        for (int j = 0; j < 16; ++j) {
            float x = sf[j >> 2][j & 3], hh;
            hh = fmaxf(m0, x); x = fminf(m0, x); m0 = hh;
            hh = fmaxf(m1, x); x = fminf(m1, x); m1 = hh;
            hh = fmaxf(m2, x); x = fminf(m2, x); m2 = hh;
            m3 = fmaxf(m3, x);
        }
        float wm = 0.f, hm = 0.f;
        #pragma unroll
        for (int k = 0; k < SUB; ++k) {
            wm = fmaxf(wm, whm[(b * SUB + k) * 2 + 0]);
            hm = fmaxf(hm, whm[(b * SUB + k) * 2 + 1]);
        }
        float lb = m3 * 0.999f;   // relative margin 1e-3 >> fp rounding of bound exprs
        int bxlo = 0, bxhi = 31, bylo = 0, byhi = 31;
        if (lb > 1e-6f) {
            // necessary for iou>=lb: p0 in [t0+lb*gw-wm, t2-lb*gw], y analog.
            // bkt monotone => exact bucket bounds; 1e-5 abs slack >> 5e-7 fp error.
            bxlo = bkt(t0 + lb * gw - wm - 1e-5f);
            bxhi = bkt(t2 - lb * gw + 1e-5f);
            bylo = bkt(t1 + lb * gh - hm - 1e-5f);
            byhi = bkt(t3 - lb * gh + 1e-5f);
        }
        if (lane < NBX) {
            bool inx = (lane >= bxlo) && (lane <= bxhi);
            int lo = (int)offb[lane * NBY + bylo];
            int hi = (int)offb[lane * NBY + byhi + 1];
            seg_lo[lane] = lo;
            seg_hi[lane] = inx ? hi : lo;   // empty column outside window
        }
    }
    __syncthreads();

    // ---- stage 1: wave-per-column, 2-wide chains + DEPTH-2 pipeline ----
    u64 a0 = 0, a1 = 0, a2 = 0, a3 = 0;      // chain A (even 64-groups)
    u64 c0 = 0, c1 = 0, c2 = 0, c3 = 0;      // chain B (odd 64-groups)
    for (int s = wv; s < NBX; s += 4) {
        const int lo = seg_lo[s];
        const int n = seg_hi[s] - lo;        // wave-uniform trip count
        const float4* __restrict__ bp = boxb + lo;
        const u32*    __restrict__ ip = idxb + lo;

        // pipeline slots: (qa0,qb0)=current pair, (qa1,qb1)=next pair
        float4 qa0 = {0,0,0,0}, qb0 = {0,0,0,0}, qa1 = {0,0,0,0}, qb1 = {0,0,0,0};
        u32 oa0 = 0, ob0 = 0, oa1 = 0, ob1 = 0;
        if (lane < n)       { qa0 = bp[lane];       oa0 = ip[lane]; }
        if (lane + 64 < n)  { qb0 = bp[lane + 64];  ob0 = ip[lane + 64]; }
        if (lane + 128 < n) { qa1 = bp[lane + 128]; oa1 = ip[lane + 128]; }
        if (lane + 192 < n) { qb1 = bp[lane + 192]; ob1 = ip[lane + 192]; }

        for (int base = 0; base < n; base += 128) {
            // prefetch 2 iterations ahead (~520 compute-cycles before use)
            float4 qa2 = qa1, qb2 = qb1; u32 oa2 = oa1, ob2 = ob1;
            const int ja = base + 256 + lane, jb = base + 320 + lane;
            if (ja < n) { qa2 = bp[ja]; oa2 = ip[ja]; }
            if (jb < n) { qb2 = bp[jb]; ob2 = ip[jb]; }

            if (base + lane < n) {
                u64 x; IOUKEY(qa0, oa0, x);
                INS4(x, a0, a1, a2, a3);
            }
            if (base + 64 + lane < n) {
                u64 x; IOUKEY(qb0, ob0, x);
                INS4(x, c0, c1, c2, c3);
            }
            qa0 = qa1; oa0 = oa1; qb0 = qb1; ob0 = ob1;
            qa1 = qa2; oa1 = oa2; qb1 = qb2; ob1 = ob2;
        }
    }
    // merge chain B into A (both sorted desc): bitonic 8->4
    ceu(a0, c3); ceu(a1, c2); ceu(a2, c1); ceu(a3, c0);
    ceu(a0, a2); ceu(a1, a3); ceu(a0, a1); ceu(a2, a3);

    #pragma unroll
    for (int d = 32; d >= 1; d >>= 1) {
        u64 n0 = __shfl_down(a0, d, 64);
        u64 n1 = __shfl_down(a1, d, 64);
        u64 n2 = __shfl_down(a2, d, 64);
        u64 n3 = __shfl_down(a3, d, 64);
        ceu(a0, n3); ceu(a1, n2); ceu(a2, n1); ceu(a3, n0);
        ceu(a0, a2); ceu(a1, a3); ceu(a0, a1); ceu(a2, a3);
    }
    if (lane == 0) { sm[wv][0] = a0; sm[wv][1] = a1; sm[wv][2] = a2; sm[wv][3] = a3; }
    __syncthreads();

    if (tid == 0) {
        u64 f0 = 0, f1 = 0, f2 = 0, f3 = 0;
        #pragma unroll
        for (int j = 0; j < 16; ++j) {
            u64 x = sm[j >> 2][j & 3];
            INS4(x, f0, f1, f2, f3);
        }
        const float gcx = (t0 + t2) * 0.5f;
        const float gcy = (t1 + t3) * 0.5f;
        const float4* __restrict__ pv =
            (const float4*)(rois + ((size_t)(2 * b + 1)) * P * 4);
        float4* __restrict__ o4 = (float4*)out;

        u64 ks[KTOP] = {f0, f1, f2, f3};
        #pragma unroll
        for (int k = 0; k < KTOP; ++k) {
            int idx = (int)(~(u32)ks[k]) & (P - 1);       // decode original prior index
            float4 q = pv[idx];
            float pcx = (q.x + q.z) * 0.5f;
            float pcy = (q.y + q.w) * 0.5f;
            float pw  = q.z - q.x;
            float ph  = q.w - q.y;
            float4 r;
            r.x = (gcx - pcx) / (0.1f * pw);
            r.y = (gcy - pcy) / (0.1f * ph);
            r.z = logf(gw / pw) / 0.2f;
            r.w = logf(gh / ph) / 0.2f;
            o4[((size_t)(b * NG + g)) * KTOP + k] = r;
        }
    }
}

extern "C" void kernel_launch(void* const* d_in, const int* in_sizes, int n_in,
                              void* d_out, int out_size, void* d_ws, size_t ws_size,
                              hipStream_t stream) {
    const float* rois    = (const float*)d_in[0];
    const float* targets = (const float*)d_in[1];
    float* out = (float*)d_out;

    char* w = (char*)d_ws;
    float4* sbox = (float4*)(w);                                    // 8 MB
    u32*    sidx = (u32*)  (w + (size_t)B * P * 16);                // 2 MB
    u32*    cnt  = (u32*)  (w + (size_t)B * P * 20);                // 1 MB
    u32*    off  = (u32*)  (w + (size_t)B * P * 24);                // 65.6 KB
    float*  whm  = (float*)(w + (size_t)B * P * 24 + 66560);        // 2 KB

    k_hist<<<dim3(B * SUB), dim3(256), 0, stream>>>(rois, cnt, whm);
    k_scat<<<dim3(B * SUB), dim3(256), 0, stream>>>(rois, cnt, sbox, sidx, off);
    k_main<<<dim3(B * NG),  dim3(256), 0, stream>>>(rois, targets, sbox, sidx, off, whm, out);
}